// Round 10
// baseline (415.094 us; speedup 1.0000x reference)
//
#include <hip/hip_runtime.h>
#include <hip/hip_bf16.h>
#include <stdint.h>

#define M_DIM 16384   // 8 * 2048
#define N_DIM 2048    // OUT_F
#define K_DIM 2048    // IN_F

typedef __attribute__((ext_vector_type(8))) __bf16 bf16x8;
typedef __attribute__((ext_vector_type(4))) float f32x4;

__device__ __forceinline__ unsigned short f2bf(float f) {
  unsigned int u = __builtin_bit_cast(unsigned int, f);
  u += 0x7FFFu + ((u >> 16) & 1u);   // round-to-nearest-even
  return (unsigned short)(u >> 16);
}

__device__ __forceinline__ float sigmoidf_(float x) {
  return 1.0f / (1.0f + __expf(-x));
}

// ---------------- kernel 1: X f32 -> bf16 ----------------
__global__ __launch_bounds__(256) void convert_x(const float4* __restrict__ x,
                                                 uint4* __restrict__ xb) {
  int idx = blockIdx.x * 256 + threadIdx.x;   // one uint4 (8 bf16) per thread
  float4 a = x[idx * 2];
  float4 b = x[idx * 2 + 1];
  uint4 r;
  r.x = (unsigned)f2bf(a.x) | ((unsigned)f2bf(a.y) << 16);
  r.y = (unsigned)f2bf(a.z) | ((unsigned)f2bf(a.w) << 16);
  r.z = (unsigned)f2bf(b.x) | ((unsigned)f2bf(b.y) << 16);
  r.w = (unsigned)f2bf(b.z) | ((unsigned)f2bf(b.w) << 16);
  xb[idx] = r;
}

// ---------------- kernel 2: weight materialization (producer-aligned) -------
// XCD x (blockIdx%8) materializes exactly B panel o in [x*256, x*256+256) --
// the panel GEMM-XCD x reads (B stays dirty-resident in its birth L2).
__global__ __launch_bounds__(256) void make_w(const float4* __restrict__ pw,
                                              const float4* __restrict__ nw,
                                              const float* __restrict__ exps,
                                              const float* __restrict__ maskw,
                                              const float* __restrict__ scale,
                                              unsigned short* __restrict__ wout) {
  const int beta = blockIdx.x;          // 16384 blocks
  const int xcd = beta & 7;
  const int j = beta >> 3;              // 0..2047
  const int o = xcd * 256 + (j >> 3);   // output row (B panel row)
  const int iblk = j & 7;               // 256-wide i chunk
  int idx = (o * 2048 + iblk * 256) + threadIdx.x;   // flat (o*K + i) in float4s
  float4 p = pw[idx];
  float4 n = nw[idx];
  float s = scale[0];
  float c0 = sigmoidf_(maskw[0]) * exps[0] * s;
  float c1 = sigmoidf_(maskw[1]) * exps[1] * s;
  float c2 = sigmoidf_(maskw[2]) * exps[2] * s;
  float c3 = sigmoidf_(maskw[3]) * exps[3] * s;
  float w = (sigmoidf_(p.x) - sigmoidf_(n.x)) * c0
          + (sigmoidf_(p.y) - sigmoidf_(n.y)) * c1
          + (sigmoidf_(p.z) - sigmoidf_(n.z)) * c2
          + (sigmoidf_(p.w) - sigmoidf_(n.w)) * c3;
  wout[idx] = f2bf(w);
}

// ---------------- kernel 3: bias ----------------
__global__ __launch_bounds__(256) void make_bias(const float* __restrict__ pb,
                                                 const float* __restrict__ nb,
                                                 const float* __restrict__ bexps,
                                                 const float* __restrict__ bscale,
                                                 float* __restrict__ bias) {
  int o = blockIdx.x * 256 + threadIdx.x;
  if (o < N_DIM) {
    float x = 0.f;
#pragma unroll
    for (int n = 0; n < 4; ++n) x += (pb[o * 4 + n] - nb[o * 4 + n]) * bexps[n];
    float xc = fminf(fmaxf(x, -1.f), 1.f);
    float mag = rintf(fabsf(xc) * 15.f) * (1.f / 15.f);
    float sgn = (xc > 0.f) ? 1.f : ((xc < 0.f) ? -1.f : 0.f);
    bias[o] = mag * sgn * bscale[0];
  }
}

// ---------------- kernel 4: 256x256 GEMM, 4 waves x 128x128, BK=32 ----------
// R9 post-mortem: anti-phase roles regressed (convoy not breakable by role
// games under a shared barrier); R6-R8 invariant 2700cy/iter = serial sum of
// CU-shared LDS pipe (96 ds_read_b128 x 12cy = 1150) + stage writes (256) +
// matrix pipe (1030/SIMD). Unfixable by depth/gates/roles -> reduce the LDS
// INSTRUCTION COUNT per FLOP: 4 waves (2x2), each owning 128x128: per iter
// 16 reads feed 64 MFMA per wave (4:1 vs 2.7:1) -> per-CU reads 96->64
// (768cy), convoy-serial ~2100cy/iter. acc=256 regs/lane -> 1 wave/SIMD
// (launch_bounds(256,1)); R8 proved TLP depth was not the binding factor.
// Schedule = R8's exactly: 4-deep buffers, stage t+3 during t, counted gates.
//
// Per-iter: {16 ds_read_b128; 8x gload_lds(t+3); 64 MFMA; VMCNT(8); BAR}.
// vmcnt: 8 loads/thread/iter; prologue 24 (tiles 0,1,2), VMCNT(16) -> tile 0
// landed; end of iter t VMCNT(8) -> tiles <= t+2 landed. VMCNT(0) post-loop.
//
// LDS tile layout (A and B identical), tile = 256 r x 32 k = 16 KB:
//   fr = r & 127, hi = r >> 7; slot = ((k>>3) + 4*hi) ^ (fr & 7)
//   byte = fr*128 + slot*16. Linear gload dest + inverse-mapped global src
//   (rule 21); reads 2 lanes/bank = conflict-free (m136; R8 measured 0).

#define BM 256
#define BN 256
#define BK 32
#define NT (K_DIM / BK)   // 64
#define NBUF 4

__device__ __forceinline__ void gload16(const void* g, void* l) {
  __builtin_amdgcn_global_load_lds(
      (const __attribute__((address_space(1))) unsigned int*)g,
      (__attribute__((address_space(3))) unsigned int*)l, 16, 0, 0);
}

#define VMCNT(n) asm volatile("s_waitcnt vmcnt(" #n ")" ::: "memory")
#define BAR() __builtin_amdgcn_s_barrier()

__global__ __launch_bounds__(256, 1) void gemm_bias(const unsigned short* __restrict__ X,
                                                    const unsigned short* __restrict__ W,
                                                    const float* __restrict__ bias,
                                                    float* __restrict__ out) {
  __shared__ unsigned short sA[NBUF][128 * 64];   // 4 x 16 KiB
  __shared__ unsigned short sB[NBUF][128 * 64];   // 4 x 16 KiB  (128 KiB total)

  const int tid = threadIdx.x;
  // Locality swizzle (R5, kept): one bn-column per XCD; B panel L2-private.
  const int bn = (int)blockIdx.x & 7;    // == XCD (dispatch round-robin)
  const int bm = (int)blockIdx.x >> 3;   // 0..63
  const int row0 = bm * BM, col0 = bn * BN;

  const int w = tid >> 6, l = tid & 63;
  const int wr = w >> 1;        // 0..1  (M wave group)
  const int wc = w & 1;         // 0..1  (N wave group)
  const int lr = l & 15;
  const int lk4 = l >> 4;       // 0..3
  const int lr7 = lr & 7;

  const unsigned short* Ag = X + (size_t)row0 * K_DIM;
  const unsigned short* Bg = W + (size_t)col0 * K_DIM;

  // ---- staging: one gload16/thread per round (4KB round, fr rr..rr+31)
  // dst (linear): fr = rr + (tid>>3), slot = tid&7, byte = fr*128 + slot*16.
  // src (inverse map): pre = slot ^ (fr&7); r = fr + 128*(pre>>2), k=(pre&3)*8.
  const int s_frl = tid >> 3;                       // 0..31 (fr - rr)
  const int s_pre = (tid & 7) ^ ((tid >> 3) & 7);
  const int s_rglo = 128 * (s_pre >> 2);            // 0 or 128
  const int s_k = (s_pre & 3) * 8;
  const int s_dst = tid * 8;                        // ushort offset in round

  auto stage = [&](unsigned short* lbase, const unsigned short* gbase,
                   int rr, int tk) {
    gload16(gbase + (size_t)(rr + s_frl + s_rglo) * K_DIM + tk * BK + s_k,
            lbase + rr * 64 + s_dst);
  };

  auto stage_tile = [&](unsigned short* la, unsigned short* lb, int tk) {
    stage(la, Ag, 0, tk);
    stage(la, Ag, 32, tk);
    stage(la, Ag, 64, tk);
    stage(la, Ag, 96, tk);
    stage(lb, Bg, 0, tk);
    stage(lb, Bg, 32, tk);
    stage(lb, Bg, 64, tk);
    stage(lb, Bg, 96, tk);
  };

  // ---- fragment reads (2 lanes/bank = conflict-free)
  auto rdA = [&](const unsigned short* base, int mf) -> bf16x8 {
    int fr = mf * 16 + lr;                   // wave rows wr*128 + ...: hi = wr
    int slot = (lk4 + 4 * wr) ^ lr7;
    return *(const bf16x8*)&base[fr * 64 + slot * 8];
  };
  auto rdB = [&](const unsigned short* base, int nf) -> bf16x8 {
    int fr = nf * 16 + lr;                   // wave cols wc*128 + ...: hi = wc
    int slot = (lk4 + 4 * wc) ^ lr7;
    return *(const bf16x8*)&base[fr * 64 + slot * 8];
  };

  f32x4 acc[8][8] = {};
  bf16x8 a[8], b[8];

  // ---- prologue: stage tiles 0,1,2 (24 loads/thread in flight)
#pragma unroll
  for (int pt = 0; pt < 3; ++pt) stage_tile(sA[pt], sB[pt], pt);
  VMCNT(16);   // tile 0 landed (tiles 1,2 = 16 loads outstanding)
  BAR();

  for (int t = 0; t < NT; ++t) {
    const unsigned short* pa = sA[t & 3];
    const unsigned short* pb = sB[t & 3];
    unsigned short* qa = sA[(t + 3) & 3];
    unsigned short* qb = sB[(t + 3) & 3];
    const int tk3 = (t + 3) & (NT - 1);   // wrapped tail: junk into dead buf

    // reads of tile t (16 x ds_read_b128)
#pragma unroll
    for (int mf = 0; mf < 8; ++mf) a[mf] = rdA(pa, mf);
#pragma unroll
    for (int nf = 0; nf < 8; ++nf) b[nf] = rdB(pb, nf);

    // stage tile t+3 (buffer dead since iter t-1)
    stage_tile(qa, qb, tk3);

    // 64 independent MFMAs
    __builtin_amdgcn_s_setprio(1);
#pragma unroll
    for (int mf = 0; mf < 8; ++mf)
#pragma unroll
      for (int nf = 0; nf < 8; ++nf)
        acc[mf][nf] = __builtin_amdgcn_mfma_f32_16x16x32_bf16(
            a[mf], b[nf], acc[mf][nf], 0, 0, 0);
    __builtin_amdgcn_s_setprio(0);

    VMCNT(8);   // tiles <= t+2 landed (only t+3's 8 loads outstanding)
    BAR();
  }
  VMCNT(0);     // drain junk stages: no DMA outstanding into freed LDS

  // ---- epilogue: bias + store (C/D layout: col=lane&15, row=(lane>>4)*4+reg)
  float bv[8];
#pragma unroll
  for (int nf = 0; nf < 8; ++nf) bv[nf] = bias[col0 + wc * 128 + nf * 16 + lr];
  const int orow = lk4 * 4;
#pragma unroll
  for (int mf = 0; mf < 8; ++mf) {
#pragma unroll
    for (int nf = 0; nf < 8; ++nf) {
      const int colg = col0 + wc * 128 + nf * 16 + lr;
#pragma unroll
      for (int r = 0; r < 4; ++r) {
        int rowg = row0 + wr * 128 + mf * 16 + orow + r;
        out[(size_t)rowg * N_DIM + colg] = acc[mf][nf][r] + bv[nf];
      }
    }
  }
}

// ---------------- launch ----------------
extern "C" void kernel_launch(void* const* d_in, const int* in_sizes, int n_in,
                              void* d_out, int out_size, void* d_ws, size_t ws_size,
                              hipStream_t stream) {
  const float* input  = (const float*)d_in[0];
  const float* pweight = (const float*)d_in[1];
  const float* nweight = (const float*)d_in[2];
  const float* exps   = (const float*)d_in[3];
  const float* bexps  = (const float*)d_in[4];
  const float* maskw  = (const float*)d_in[5];
  const float* scale  = (const float*)d_in[6];
  const float* pbias  = (const float*)d_in[7];
  const float* nbias  = (const float*)d_in[8];
  const float* bscale = (const float*)d_in[9];
  float* out = (float*)d_out;

  unsigned short* Xb = (unsigned short*)d_ws;                                        // 64 MB
  unsigned short* Wb = (unsigned short*)((char*)d_ws + (size_t)M_DIM * K_DIM * 2);   // 8 MB
  float* bias = (float*)((char*)d_ws + (size_t)M_DIM * K_DIM * 2 + (size_t)N_DIM * K_DIM * 2);

  convert_x<<<(M_DIM * (size_t)K_DIM) / 8 / 256, 256, 0, stream>>>((const float4*)input, (uint4*)Xb);
  make_w<<<((size_t)N_DIM * K_DIM) / 256, 256, 0, stream>>>(
      (const float4*)pweight, (const float4*)nweight, exps, maskw, scale, Wb);
  make_bias<<<(N_DIM + 255) / 256, 256, 0, stream>>>(pbias, nbias, bexps, bscale, bias);

  dim3 grid((M_DIM / BM) * (N_DIM / BN));   // 64 * 8 = 512
  gemm_bias<<<grid, 256, 0, stream>>>(Xb, Wb, bias, out);
}

// Round 11
// 200.033 us; speedup vs baseline: 2.0751x; 2.0751x over previous
//
#include <hip/hip_runtime.h>
#include <hip/hip_bf16.h>
#include <stdint.h>

#define M_DIM 16384   // 8 * 2048
#define N_DIM 2048    // OUT_F
#define K_DIM 2048    // IN_F

typedef __attribute__((ext_vector_type(8))) __bf16 bf16x8;
typedef __attribute__((ext_vector_type(4))) float f32x4;

__device__ __forceinline__ unsigned short f2bf(float f) {
  unsigned int u = __builtin_bit_cast(unsigned int, f);
  u += 0x7FFFu + ((u >> 16) & 1u);   // round-to-nearest-even
  return (unsigned short)(u >> 16);
}

__device__ __forceinline__ float sigmoidf_(float x) {
  return 1.0f / (1.0f + __expf(-x));
}

// ---------------- fused prep: convert_x + make_w + bias in ONE launch -------
// Blocks [0,16384): X f32->bf16 (8 elems/thread).
// Blocks [16384,32768): W materialization, producer-XCD-aligned: the range
//   starts at 16384 % 8 == 0, so (blockIdx-16384)&7 == blockIdx&7 == dispatch
//   XCD; XCD x writes exactly B panel [x*256, x*256+256) -- the panel GEMM
//   XCD x reads (B stays dirty-resident in its birth L2).
// Blocks [32768,32776): bias (exact: bias_raw = k/15, rintf matches jnp.round).
__global__ __launch_bounds__(256) void prep_all(const float4* __restrict__ x,
                                                uint4* __restrict__ xb,
                                                const float4* __restrict__ pw,
                                                const float4* __restrict__ nw,
                                                const float* __restrict__ exps,
                                                const float* __restrict__ maskw,
                                                const float* __restrict__ scale,
                                                unsigned short* __restrict__ wout,
                                                const float* __restrict__ pb,
                                                const float* __restrict__ nb,
                                                const float* __restrict__ bexps,
                                                const float* __restrict__ bscale,
                                                float* __restrict__ bias) {
  const int blk = blockIdx.x;
  if (blk < 16384) {
    // ---- convert X
    int idx = blk * 256 + threadIdx.x;   // one uint4 (8 bf16) per thread
    float4 a = x[idx * 2];
    float4 b = x[idx * 2 + 1];
    uint4 r;
    r.x = (unsigned)f2bf(a.x) | ((unsigned)f2bf(a.y) << 16);
    r.y = (unsigned)f2bf(a.z) | ((unsigned)f2bf(a.w) << 16);
    r.z = (unsigned)f2bf(b.x) | ((unsigned)f2bf(b.y) << 16);
    r.w = (unsigned)f2bf(b.z) | ((unsigned)f2bf(b.w) << 16);
    xb[idx] = r;
  } else if (blk < 32768) {
    // ---- materialize W (producer-aligned)
    const int beta = blk - 16384;         // 16384 blocks, beta%8 == blk%8
    const int xcd = beta & 7;
    const int j = beta >> 3;              // 0..2047
    const int o = xcd * 256 + (j >> 3);   // output row (B panel row)
    const int iblk = j & 7;               // 256-wide i chunk
    int idx = (o * 2048 + iblk * 256) + threadIdx.x;   // flat (o*K+i) in float4s
    float4 p = pw[idx];
    float4 n = nw[idx];
    float s = scale[0];
    float c0 = sigmoidf_(maskw[0]) * exps[0] * s;
    float c1 = sigmoidf_(maskw[1]) * exps[1] * s;
    float c2 = sigmoidf_(maskw[2]) * exps[2] * s;
    float c3 = sigmoidf_(maskw[3]) * exps[3] * s;
    float w = (sigmoidf_(p.x) - sigmoidf_(n.x)) * c0
            + (sigmoidf_(p.y) - sigmoidf_(n.y)) * c1
            + (sigmoidf_(p.z) - sigmoidf_(n.z)) * c2
            + (sigmoidf_(p.w) - sigmoidf_(n.w)) * c3;
    wout[idx] = f2bf(w);
  } else {
    // ---- bias
    int o = (blk - 32768) * 256 + threadIdx.x;
    if (o < N_DIM) {
      float xv = 0.f;
#pragma unroll
      for (int n = 0; n < 4; ++n) xv += (pb[o * 4 + n] - nb[o * 4 + n]) * bexps[n];
      float xc = fminf(fmaxf(xv, -1.f), 1.f);
      float mag = rintf(fabsf(xc) * 15.f) * (1.f / 15.f);
      float sgn = (xc > 0.f) ? 1.f : ((xc < 0.f) ? -1.f : 0.f);
      bias[o] = mag * sgn * bscale[0];
    }
  }
}

// ---------------- GEMM: 256x256, BK=64, barrier-halved 4-phase (R6 best) ----
// Measured-best form (R6: 144us, MfmaUtil 41%, 0 bank conflicts). Schedule
// variants R2-R10 (gate depth 2-4 phases, read-ahead, anti-phase roles,
// 128x128/wave) were all neutral-to-regressive; this is the keeper.
// Phase = {ds_reads; 2x stage; MFMA; [vmcnt gate]; s_barrier}, 4 bar/tile.
//
// Rounds (one gload_lds/thread, 64 rows): R0:A{0-63} R1:A{128-191}
// R2:B{0-31,64-95} R3:B{128-159,192-223} R4:B{32-63,96-127}
// R5:B{160-191,224-255} R6:A{64-127} R7:A{192-255}
// Staging: P0(t)->R0R1(t+1)  P1->R2R3  P2->R4R5  P3->R6R7  (into buf q).
// Reads:   P0(t): R0-R3(t)   P1: R4R5(t)  P2: R6R7(t)  P3: none.
// Gates: end-P0 VMCNT(4) retires R4R5(t); end-P1 VMCNT(4) retires R6R7(t);
//   end-P2 none; end-P3 VMCNT(4) retires R0-R3(t+1). Never drains mid-loop.

#define BM 256
#define BN 256
#define BK 64
#define NT (K_DIM / BK)   // 32

__device__ __forceinline__ void gload16(const void* g, void* l) {
  __builtin_amdgcn_global_load_lds(
      (const __attribute__((address_space(1))) unsigned int*)g,
      (__attribute__((address_space(3))) unsigned int*)l, 16, 0, 0);
}

#define VMCNT(n) asm volatile("s_waitcnt vmcnt(" #n ")" ::: "memory")
#define BAR() __builtin_amdgcn_s_barrier()

__global__ __launch_bounds__(512, 2) void gemm_bias(const unsigned short* __restrict__ X,
                                                    const unsigned short* __restrict__ W,
                                                    const float* __restrict__ bias,
                                                    float* __restrict__ out) {
  __shared__ unsigned short sA[2][BM * BK];   // 64 KiB
  __shared__ unsigned short sB[2][BN * BK];   // 64 KiB

  const int tid = threadIdx.x;
  // Locality swizzle: one bn-column per XCD; B panel (1 MB) L2-private,
  // written there by prep_all's make_w range.
  const int bn = (int)blockIdx.x & 7;    // == XCD (dispatch round-robin)
  const int bm = (int)blockIdx.x >> 3;   // 0..63
  const int row0 = bm * BM, col0 = bn * BN;

  const int w = tid >> 6, l = tid & 63;
  const int wr = w >> 2;        // 0..1  (M wave group)
  const int wc = w & 3;         // 0..3  (N wave group)
  const int lr = l & 15;
  const int lk4 = l >> 4;       // 0..3
  const int l7 = l & 7;

  const unsigned short* Ag = X + (size_t)row0 * K_DIM;
  const unsigned short* Bg = W + (size_t)col0 * K_DIM;

  // staging geometry: thread t -> row rb+((t>>3)&31); global col16 pre-swizzled
  const int srl = (tid >> 3) & 31;
  const int sc16 = (tid & 7) ^ ((tid >> 3) & 7);      // inverse-swizzled source
  const int shi = tid >> 8;                           // wave-uniform chunk select
  const int slin = ((tid >> 3) & 24) * 64 + (tid & 63) * 8;  // linear LDS dest

  auto stage = [&](unsigned short* lbase, const unsigned short* gbase,
                   int rb0, int rb1, int tk) {
    int rb = shi ? rb1 : rb0;
    int trow = rb + srl;
    gload16(gbase + (size_t)trow * K_DIM + tk * BK + sc16 * 8,
            lbase + rb * 64 + slin);
  };

  auto rdA = [&](const unsigned short* base, int mf, int ks) -> bf16x8 {
    int trow = wr * 128 + mf * 16 + lr;
    int c16l = (ks * 4 + lk4) ^ l7;
    return *(const bf16x8*)&base[trow * 64 + c16l * 8];
  };
  auto rdB = [&](const unsigned short* base, int nf, int ks) -> bf16x8 {
    int trow = wc * 64 + nf * 16 + lr;
    int c16l = (ks * 4 + lk4) ^ l7;
    return *(const bf16x8*)&base[trow * 64 + c16l * 8];
  };

  f32x4 acc[8][4] = {};
  bf16x8 a[4][2], b[4][2];

#define PHASE_MFMA(mh, nh)                                                    \
  __builtin_amdgcn_s_setprio(1);                                              \
  _Pragma("unroll") for (int i = 0; i < 4; ++i)                               \
  _Pragma("unroll") for (int j = 0; j < 2; ++j)                               \
  _Pragma("unroll") for (int ks = 0; ks < 2; ++ks)                            \
      acc[(mh) * 4 + i][(nh) * 2 + j] = __builtin_amdgcn_mfma_f32_16x16x32_bf16( \
          a[i][ks], b[(nh) * 2 + j][ks], acc[(mh) * 4 + i][(nh) * 2 + j], 0, 0, 0); \
  __builtin_amdgcn_s_setprio(0);

  // ---- prologue: stage tile 0 (rounds R0..R7, program order = round order)
  {
    unsigned short* qa = sA[0];
    unsigned short* qb = sB[0];
    stage(qa, Ag, 0, 32, 0);    // R0
    stage(qa, Ag, 128, 160, 0); // R1
    stage(qb, Bg, 0, 64, 0);    // R2
    stage(qb, Bg, 128, 192, 0); // R3
    stage(qb, Bg, 32, 96, 0);   // R4
    stage(qb, Bg, 160, 224, 0); // R5
    stage(qa, Ag, 64, 96, 0);   // R6
    stage(qa, Ag, 192, 224, 0); // R7
  }
  VMCNT(4);   // R0-R3(0) complete; R4-R7(0) in flight
  BAR();

  for (int t = 0; t < NT; ++t) {
    const int p = t & 1, q = p ^ 1;
    const bool last = (t == NT - 1);
    const unsigned short* pa = sA[p];
    const unsigned short* pb = sB[p];
    unsigned short* qa = sA[q];
    unsigned short* qb = sB[q];

    // ---- P0: reads A(mh0)+B(nf0,1) of t; stage R0R1(t+1); MFMA (0,0)
#pragma unroll
    for (int i = 0; i < 4; ++i)
#pragma unroll
      for (int ks = 0; ks < 2; ++ks) a[i][ks] = rdA(pa, i, ks);
#pragma unroll
    for (int j = 0; j < 2; ++j)
#pragma unroll
      for (int ks = 0; ks < 2; ++ks) b[j][ks] = rdB(pb, j, ks);
    if (!last) { stage(qa, Ag, 0, 32, t + 1); stage(qa, Ag, 128, 160, t + 1); }
    PHASE_MFMA(0, 0);
    if (!last) { VMCNT(4); } else { VMCNT(2); }   // R4,R5(t) done
    BAR();

    // ---- P1: reads B(nf2,3) of t; stage R2R3(t+1); MFMA (0,1)
#pragma unroll
    for (int j = 2; j < 4; ++j)
#pragma unroll
      for (int ks = 0; ks < 2; ++ks) b[j][ks] = rdB(pb, j, ks);
    if (!last) { stage(qb, Bg, 0, 64, t + 1); stage(qb, Bg, 128, 192, t + 1); }
    PHASE_MFMA(0, 1);
    if (!last) { VMCNT(4); } else { VMCNT(0); }   // R6,R7(t) done
    BAR();

    // ---- P2: reads A(mh1) of t; stage R4R5(t+1); MFMA (1,0)
#pragma unroll
    for (int i = 0; i < 4; ++i)
#pragma unroll
      for (int ks = 0; ks < 2; ++ks) a[i][ks] = rdA(pa, 4 + i, ks);
    if (!last) { stage(qb, Bg, 32, 96, t + 1); stage(qb, Bg, 160, 224, t + 1); }
    PHASE_MFMA(1, 0);
    BAR();                                         // no gate (P3 reads nothing)

    // ---- P3: no reads; stage R6R7(t+1); MFMA (1,1)
    if (!last) { stage(qa, Ag, 64, 96, t + 1); stage(qa, Ag, 192, 224, t + 1); }
    PHASE_MFMA(1, 1);
    if (!last) { VMCNT(4); }                       // R0-R3(t+1) done
    BAR();
  }

  // ---- epilogue: bias + store (C/D layout: col=lane&15, row=(lane>>4)*4+reg)
  float bv[4];
#pragma unroll
  for (int nf = 0; nf < 4; ++nf) bv[nf] = bias[col0 + wc * 64 + nf * 16 + lr];
  const int orow = lk4 * 4;
#pragma unroll
  for (int mf = 0; mf < 8; ++mf) {
#pragma unroll
    for (int nf = 0; nf < 4; ++nf) {
      const int colg = col0 + wc * 64 + nf * 16 + lr;
#pragma unroll
      for (int r = 0; r < 4; ++r) {
        int rowg = row0 + wr * 128 + mf * 16 + orow + r;
        out[(size_t)rowg * N_DIM + colg] = acc[mf][nf][r] + bv[nf];
      }
    }
  }
#undef PHASE_MFMA
}

// ---------------- launch ----------------
extern "C" void kernel_launch(void* const* d_in, const int* in_sizes, int n_in,
                              void* d_out, int out_size, void* d_ws, size_t ws_size,
                              hipStream_t stream) {
  const float* input  = (const float*)d_in[0];
  const float* pweight = (const float*)d_in[1];
  const float* nweight = (const float*)d_in[2];
  const float* exps   = (const float*)d_in[3];
  const float* bexps  = (const float*)d_in[4];
  const float* maskw  = (const float*)d_in[5];
  const float* scale  = (const float*)d_in[6];
  const float* pbias  = (const float*)d_in[7];
  const float* nbias  = (const float*)d_in[8];
  const float* bscale = (const float*)d_in[9];
  float* out = (float*)d_out;

  unsigned short* Xb = (unsigned short*)d_ws;                                        // 64 MB
  unsigned short* Wb = (unsigned short*)((char*)d_ws + (size_t)M_DIM * K_DIM * 2);   // 8 MB
  float* bias = (float*)((char*)d_ws + (size_t)M_DIM * K_DIM * 2 + (size_t)N_DIM * K_DIM * 2);

  // one fused prep launch: 16384 convert blocks + 16384 make_w + 8 bias
  prep_all<<<16384 + 16384 + 8, 256, 0, stream>>>(
      (const float4*)input, (uint4*)Xb,
      (const float4*)pweight, (const float4*)nweight, exps, maskw, scale, Wb,
      pbias, nbias, bexps, bscale, bias);

  dim3 grid((M_DIM / BM) * (N_DIM / BN));   // 64 * 8 = 512
  gemm_bias<<<grid, 512, 0, stream>>>(Xb, Wb, bias, out);
}

// Round 12
// 195.106 us; speedup vs baseline: 2.1275x; 1.0253x over previous
//
#include <hip/hip_runtime.h>
#include <hip/hip_bf16.h>
#include <stdint.h>

#define M_DIM 16384   // 8 * 2048
#define N_DIM 2048    // OUT_F
#define K_DIM 2048    // IN_F

typedef __attribute__((ext_vector_type(8))) __bf16 bf16x8;
typedef __attribute__((ext_vector_type(4))) float f32x4;

__device__ __forceinline__ unsigned short f2bf(float f) {
  unsigned int u = __builtin_bit_cast(unsigned int, f);
  u += 0x7FFFu + ((u >> 16) & 1u);   // round-to-nearest-even
  return (unsigned short)(u >> 16);
}

__device__ __forceinline__ float sigmoidf_(float x) {
  return 1.0f / (1.0f + __expf(-x));
}

// ---------------- fused prep: convert_x + make_w + bias in ONE launch -------
// Blocks [0,16384): X f32->bf16. Blocks [16384,32768): W materialization,
// producer-XCD-aligned (range starts at 16384 % 8 == 0 so blk&7 == XCD; XCD x
// writes exactly B panel [x*256,(x+1)*256) -- the panel GEMM-XCD x reads).
// Blocks [32768,32776): bias (exact: bias_raw = k/15, rintf = jnp.round).
__global__ __launch_bounds__(256) void prep_all(const float4* __restrict__ x,
                                                uint4* __restrict__ xb,
                                                const float4* __restrict__ pw,
                                                const float4* __restrict__ nw,
                                                const float* __restrict__ exps,
                                                const float* __restrict__ maskw,
                                                const float* __restrict__ scale,
                                                unsigned short* __restrict__ wout,
                                                const float* __restrict__ pb,
                                                const float* __restrict__ nb,
                                                const float* __restrict__ bexps,
                                                const float* __restrict__ bscale,
                                                float* __restrict__ bias) {
  const int blk = blockIdx.x;
  if (blk < 16384) {
    int idx = blk * 256 + threadIdx.x;   // one uint4 (8 bf16) per thread
    float4 a = x[idx * 2];
    float4 b = x[idx * 2 + 1];
    uint4 r;
    r.x = (unsigned)f2bf(a.x) | ((unsigned)f2bf(a.y) << 16);
    r.y = (unsigned)f2bf(a.z) | ((unsigned)f2bf(a.w) << 16);
    r.z = (unsigned)f2bf(b.x) | ((unsigned)f2bf(b.y) << 16);
    r.w = (unsigned)f2bf(b.z) | ((unsigned)f2bf(b.w) << 16);
    xb[idx] = r;
  } else if (blk < 32768) {
    const int beta = blk - 16384;         // beta%8 == blk%8 == dispatch XCD
    const int xcd = beta & 7;
    const int j = beta >> 3;              // 0..2047
    const int o = xcd * 256 + (j >> 3);   // output row (B panel row)
    const int iblk = j & 7;               // 256-wide i chunk
    int idx = (o * 2048 + iblk * 256) + threadIdx.x;   // flat (o*K+i) in float4s
    float4 p = pw[idx];
    float4 n = nw[idx];
    float s = scale[0];
    float c0 = sigmoidf_(maskw[0]) * exps[0] * s;
    float c1 = sigmoidf_(maskw[1]) * exps[1] * s;
    float c2 = sigmoidf_(maskw[2]) * exps[2] * s;
    float c3 = sigmoidf_(maskw[3]) * exps[3] * s;
    float w = (sigmoidf_(p.x) - sigmoidf_(n.x)) * c0
            + (sigmoidf_(p.y) - sigmoidf_(n.y)) * c1
            + (sigmoidf_(p.z) - sigmoidf_(n.z)) * c2
            + (sigmoidf_(p.w) - sigmoidf_(n.w)) * c3;
    wout[idx] = f2bf(w);
  } else {
    int o = (blk - 32768) * 256 + threadIdx.x;
    if (o < N_DIM) {
      float xv = 0.f;
#pragma unroll
      for (int n = 0; n < 4; ++n) xv += (pb[o * 4 + n] - nb[o * 4 + n]) * bexps[n];
      float xc = fminf(fmaxf(xv, -1.f), 1.f);
      float mag = rintf(fabsf(xc) * 15.f) * (1.f / 15.f);
      float sgn = (xc > 0.f) ? 1.f : ((xc < 0.f) ? -1.f : 0.f);
      bias[o] = mag * sgn * bscale[0];
    }
  }
}

// ---------------- GEMM: 256x256, BK=64, barrier-halved 4-phase (R6 best) ----
// R11 change (single variable): epilogue stores are NONTEMPORAL (nt flag).
// Theory: the 131MB out-stream evicts the shared A window from L3; A is
// re-fetched 4x from HBM (FETCH=271MB ~= 4x67+67), inflating per-load return
// latency on the A staging path. nt-stores protect L3 -> A L3-resident.
// Everything else identical to the measured-best R6/R11 form (145us, 40.5%).

#define BM 256
#define BN 256
#define BK 64
#define NT (K_DIM / BK)   // 32

__device__ __forceinline__ void gload16(const void* g, void* l) {
  __builtin_amdgcn_global_load_lds(
      (const __attribute__((address_space(1))) unsigned int*)g,
      (__attribute__((address_space(3))) unsigned int*)l, 16, 0, 0);
}

#define VMCNT(n) asm volatile("s_waitcnt vmcnt(" #n ")" ::: "memory")
#define BAR() __builtin_amdgcn_s_barrier()

__global__ __launch_bounds__(512, 2) void gemm_bias(const unsigned short* __restrict__ X,
                                                    const unsigned short* __restrict__ W,
                                                    const float* __restrict__ bias,
                                                    float* __restrict__ out) {
  __shared__ unsigned short sA[2][BM * BK];   // 64 KiB
  __shared__ unsigned short sB[2][BN * BK];   // 64 KiB

  const int tid = threadIdx.x;
  // Locality swizzle: one bn-column per XCD; B panel (1 MB) L2-private,
  // written there by prep_all's make_w range.
  const int bn = (int)blockIdx.x & 7;    // == XCD (dispatch round-robin)
  const int bm = (int)blockIdx.x >> 3;   // 0..63
  const int row0 = bm * BM, col0 = bn * BN;

  const int w = tid >> 6, l = tid & 63;
  const int wr = w >> 2;        // 0..1  (M wave group)
  const int wc = w & 3;         // 0..3  (N wave group)
  const int lr = l & 15;
  const int lk4 = l >> 4;       // 0..3
  const int l7 = l & 7;

  const unsigned short* Ag = X + (size_t)row0 * K_DIM;
  const unsigned short* Bg = W + (size_t)col0 * K_DIM;

  // staging geometry: thread t -> row rb+((t>>3)&31); global col16 pre-swizzled
  const int srl = (tid >> 3) & 31;
  const int sc16 = (tid & 7) ^ ((tid >> 3) & 7);      // inverse-swizzled source
  const int shi = tid >> 8;                           // wave-uniform chunk select
  const int slin = ((tid >> 3) & 24) * 64 + (tid & 63) * 8;  // linear LDS dest

  auto stage = [&](unsigned short* lbase, const unsigned short* gbase,
                   int rb0, int rb1, int tk) {
    int rb = shi ? rb1 : rb0;
    int trow = rb + srl;
    gload16(gbase + (size_t)trow * K_DIM + tk * BK + sc16 * 8,
            lbase + rb * 64 + slin);
  };

  auto rdA = [&](const unsigned short* base, int mf, int ks) -> bf16x8 {
    int trow = wr * 128 + mf * 16 + lr;
    int c16l = (ks * 4 + lk4) ^ l7;
    return *(const bf16x8*)&base[trow * 64 + c16l * 8];
  };
  auto rdB = [&](const unsigned short* base, int nf, int ks) -> bf16x8 {
    int trow = wc * 64 + nf * 16 + lr;
    int c16l = (ks * 4 + lk4) ^ l7;
    return *(const bf16x8*)&base[trow * 64 + c16l * 8];
  };

  f32x4 acc[8][4] = {};
  bf16x8 a[4][2], b[4][2];

#define PHASE_MFMA(mh, nh)                                                    \
  __builtin_amdgcn_s_setprio(1);                                              \
  _Pragma("unroll") for (int i = 0; i < 4; ++i)                               \
  _Pragma("unroll") for (int j = 0; j < 2; ++j)                               \
  _Pragma("unroll") for (int ks = 0; ks < 2; ++ks)                            \
      acc[(mh) * 4 + i][(nh) * 2 + j] = __builtin_amdgcn_mfma_f32_16x16x32_bf16( \
          a[i][ks], b[(nh) * 2 + j][ks], acc[(mh) * 4 + i][(nh) * 2 + j], 0, 0, 0); \
  __builtin_amdgcn_s_setprio(0);

  // ---- prologue: stage tile 0 (rounds R0..R7, program order = round order)
  {
    unsigned short* qa = sA[0];
    unsigned short* qb = sB[0];
    stage(qa, Ag, 0, 32, 0);    // R0
    stage(qa, Ag, 128, 160, 0); // R1
    stage(qb, Bg, 0, 64, 0);    // R2
    stage(qb, Bg, 128, 192, 0); // R3
    stage(qb, Bg, 32, 96, 0);   // R4
    stage(qb, Bg, 160, 224, 0); // R5
    stage(qa, Ag, 64, 96, 0);   // R6
    stage(qa, Ag, 192, 224, 0); // R7
  }
  VMCNT(4);   // R0-R3(0) complete; R4-R7(0) in flight
  BAR();

  for (int t = 0; t < NT; ++t) {
    const int p = t & 1, q = p ^ 1;
    const bool last = (t == NT - 1);
    const unsigned short* pa = sA[p];
    const unsigned short* pb = sB[p];
    unsigned short* qa = sA[q];
    unsigned short* qb = sB[q];

    // ---- P0: reads A(mh0)+B(nf0,1) of t; stage R0R1(t+1); MFMA (0,0)
#pragma unroll
    for (int i = 0; i < 4; ++i)
#pragma unroll
      for (int ks = 0; ks < 2; ++ks) a[i][ks] = rdA(pa, i, ks);
#pragma unroll
    for (int j = 0; j < 2; ++j)
#pragma unroll
      for (int ks = 0; ks < 2; ++ks) b[j][ks] = rdB(pb, j, ks);
    if (!last) { stage(qa, Ag, 0, 32, t + 1); stage(qa, Ag, 128, 160, t + 1); }
    PHASE_MFMA(0, 0);
    if (!last) { VMCNT(4); } else { VMCNT(2); }   // R4,R5(t) done
    BAR();

    // ---- P1: reads B(nf2,3) of t; stage R2R3(t+1); MFMA (0,1)
#pragma unroll
    for (int j = 2; j < 4; ++j)
#pragma unroll
      for (int ks = 0; ks < 2; ++ks) b[j][ks] = rdB(pb, j, ks);
    if (!last) { stage(qb, Bg, 0, 64, t + 1); stage(qb, Bg, 128, 192, t + 1); }
    PHASE_MFMA(0, 1);
    if (!last) { VMCNT(4); } else { VMCNT(0); }   // R6,R7(t) done
    BAR();

    // ---- P2: reads A(mh1) of t; stage R4R5(t+1); MFMA (1,0)
#pragma unroll
    for (int i = 0; i < 4; ++i)
#pragma unroll
      for (int ks = 0; ks < 2; ++ks) a[i][ks] = rdA(pa, 4 + i, ks);
    if (!last) { stage(qb, Bg, 32, 96, t + 1); stage(qb, Bg, 160, 224, t + 1); }
    PHASE_MFMA(1, 0);
    BAR();                                         // no gate (P3 reads nothing)

    // ---- P3: no reads; stage R6R7(t+1); MFMA (1,1)
    if (!last) { stage(qa, Ag, 64, 96, t + 1); stage(qa, Ag, 192, 224, t + 1); }
    PHASE_MFMA(1, 1);
    if (!last) { VMCNT(4); }                       // R0-R3(t+1) done
    BAR();
  }

  // ---- epilogue: bias + NONTEMPORAL store (out is never re-read; keep it
  // out of L2/L3 so the shared A window stays L3-resident)
  float bv[4];
#pragma unroll
  for (int nf = 0; nf < 4; ++nf) bv[nf] = bias[col0 + wc * 64 + nf * 16 + lr];
  const int orow = lk4 * 4;
#pragma unroll
  for (int mf = 0; mf < 8; ++mf) {
#pragma unroll
    for (int nf = 0; nf < 4; ++nf) {
      const int colg = col0 + wc * 64 + nf * 16 + lr;
#pragma unroll
      for (int r = 0; r < 4; ++r) {
        int rowg = row0 + wr * 128 + mf * 16 + orow + r;
        __builtin_nontemporal_store(acc[mf][nf][r] + bv[nf],
                                    &out[(size_t)rowg * N_DIM + colg]);
      }
    }
  }
#undef PHASE_MFMA
}

// ---------------- launch ----------------
extern "C" void kernel_launch(void* const* d_in, const int* in_sizes, int n_in,
                              void* d_out, int out_size, void* d_ws, size_t ws_size,
                              hipStream_t stream) {
  const float* input  = (const float*)d_in[0];
  const float* pweight = (const float*)d_in[1];
  const float* nweight = (const float*)d_in[2];
  const float* exps   = (const float*)d_in[3];
  const float* bexps  = (const float*)d_in[4];
  const float* maskw  = (const float*)d_in[5];
  const float* scale  = (const float*)d_in[6];
  const float* pbias  = (const float*)d_in[7];
  const float* nbias  = (const float*)d_in[8];
  const float* bscale = (const float*)d_in[9];
  float* out = (float*)d_out;

  unsigned short* Xb = (unsigned short*)d_ws;                                        // 64 MB
  unsigned short* Wb = (unsigned short*)((char*)d_ws + (size_t)M_DIM * K_DIM * 2);   // 8 MB
  float* bias = (float*)((char*)d_ws + (size_t)M_DIM * K_DIM * 2 + (size_t)N_DIM * K_DIM * 2);

  // one fused prep launch: 16384 convert blocks + 16384 make_w + 8 bias
  prep_all<<<16384 + 16384 + 8, 256, 0, stream>>>(
      (const float4*)input, (uint4*)Xb,
      (const float4*)pweight, (const float4*)nweight, exps, maskw, scale, Wb,
      pbias, nbias, bexps, bscale, bias);

  dim3 grid((M_DIM / BM) * (N_DIM / BN));   // 64 * 8 = 512
  gemm_bias<<<grid, 512, 0, stream>>>(Xb, Wb, bias, out);
}